// Round 5
// baseline (399.454 us; speedup 1.0000x reference)
//
#include <hip/hip_runtime.h>

#define NN 50000
#define NE 800000
#define DD 128

#define SCAN_TILE 512
#define NBLK ((NN + SCAN_TILE - 1) / SCAN_TILE)   // 98
#define CPAD 4                                     // counts padded: 1 bin per 16B

typedef __attribute__((ext_vector_type(8))) short short8;
typedef __attribute__((ext_vector_type(4))) float floatx4;

// ---------------- init ----------------

__global__ void init_kernel(int* __restrict__ counts) {
    int i = blockIdx.x * blockDim.x + threadIdx.x;
    if (i < NN) counts[i * CPAD] = 0;
}

// single atomic per edge: histogram + within-node rank (padded bins)
__global__ void hist_rank(const int* __restrict__ col, int* __restrict__ counts,
                          int* __restrict__ rank) {
    int e = blockIdx.x * blockDim.x + threadIdx.x;
    if (e < NE) rank[e] = atomicAdd(&counts[col[e] * CPAD], 1);
}

// ---------------- hierarchical exclusive scan ----------------

__global__ __launch_bounds__(256) void block_reduce(const int* __restrict__ counts,
                                                    int* __restrict__ bsum) {
    __shared__ int s[256];
    int b = blockIdx.x, t = threadIdx.x;
    int i = b * SCAN_TILE + t;
    int v = 0;
    if (i < NN) v += counts[i * CPAD];
    if (i + 256 < NN && t + 256 < SCAN_TILE) v += counts[(i + 256) * CPAD];
    s[t] = v;
    __syncthreads();
    for (int o = 128; o > 0; o >>= 1) {
        if (t < o) s[t] += s[t + o];
        __syncthreads();
    }
    if (t == 0) bsum[b] = s[0];
}

__global__ __launch_bounds__(128) void scan_partials(int* __restrict__ bsum,
                                                     int* __restrict__ offsets) {
    __shared__ int s[128];
    int t = threadIdx.x;
    int v = (t < NBLK) ? bsum[t] : 0;
    s[t] = v;
    __syncthreads();
    for (int off = 1; off < 128; off <<= 1) {
        int x = (t >= off) ? s[t - off] : 0;
        __syncthreads();
        s[t] += x;
        __syncthreads();
    }
    if (t < NBLK) bsum[t] = s[t] - v;        // exclusive
    if (t == 127) offsets[NN] = s[NBLK - 1]; // == NE
}

__global__ __launch_bounds__(512) void scan_block(const int* __restrict__ counts,
                                                  const int* __restrict__ bsum,
                                                  int* __restrict__ offsets) {
    __shared__ int tmp[SCAN_TILE];
    int b = blockIdx.x, t = threadIdx.x;
    int i = b * SCAN_TILE + t;
    int v = (i < NN) ? counts[i * CPAD] : 0;
    tmp[t] = v;
    __syncthreads();
    for (int off = 1; off < SCAN_TILE; off <<= 1) {
        int x = (t >= off) ? tmp[t - off] : 0;
        __syncthreads();
        tmp[t] += x;
        __syncthreads();
    }
    if (i < NN) offsets[i] = tmp[t] - v + bsum[b];
}

// place edges into CSR slots (no atomics): epk = (row, raw ew)
__global__ void place_edges(const int* __restrict__ row, const int* __restrict__ col,
                            const float* __restrict__ ew, const int* __restrict__ offsets,
                            const int* __restrict__ rank, uint2* __restrict__ epk) {
    int e = blockIdx.x * blockDim.x + threadIdx.x;
    if (e >= NE) return;
    int c = col[e];
    uint2 p;
    p.x = (unsigned)row[e];
    p.y = __float_as_uint(ew[e]);
    epk[offsets[c] + rank[e]] = p;
}

// deg/dis from CSR: contiguous segmented sum, 4 lanes per node
__global__ void deg_dis(const int* __restrict__ offsets, const uint2* __restrict__ epk,
                        float* __restrict__ dis) {
    int t = blockIdx.x * blockDim.x + threadIdx.x;
    int i = t >> 2, l = t & 3;
    if (i >= NN) return;
    float s = 0.0f;
    int start = offsets[i], end = offsets[i + 1];
    for (int j = start + l; j < end; j += 4) s += __uint_as_float(epk[j].y);
    s += __shfl_xor(s, 1);
    s += __shfl_xor(s, 2);
    if (l == 0) dis[i] = rsqrtf(fmaxf(1.0f + s, 1e-12f));  // +1 self-loop
}

// epk.y: ew -> ew * dis[row]  (once for both layers)
__global__ void rescale(uint2* __restrict__ epk, const float* __restrict__ dis) {
    int e = blockIdx.x * blockDim.x + threadIdx.x;
    if (e < NE) {
        uint2 p = epk[e];
        epk[e].y = __float_as_uint(__uint_as_float(p.y) * dis[p.x]);
    }
}

// ---------------- bf16x3 split helpers ----------------

__device__ __forceinline__ void split_bf16(float x, unsigned short& hi, unsigned short& lo) {
    unsigned u = __float_as_uint(x);
    unsigned h = (u + 0x7FFFu + ((u >> 16) & 1u)) >> 16;   // RN-even to bf16
    hi = (unsigned short)h;
    float fh = __uint_as_float(h << 16);
    float r = x - fh;
    unsigned u2 = __float_as_uint(r);
    lo = (unsigned short)((u2 + 0x7FFFu + ((u2 >> 16) & 1u)) >> 16);
}

__global__ void prep_w(const float* __restrict__ W, unsigned short* __restrict__ whi,
                       unsigned short* __restrict__ wlo) {
    int t = blockIdx.x * blockDim.x + threadIdx.x;   // 16384
    int k = t >> 7, n = t & 127;
    unsigned short h, l;
    split_bf16(W[t], h, l);
    whi[n * DD + k] = h;
    wlo[n * DD + k] = l;
}

// ---------------- MFMA GEMM: hs[slice][m][16] = ((relu?)in[m,:] @ W) sliced ----------------
// Output written in slice-major layout for the XCD-pinned aggregation.

template <bool RELU>
__global__ __launch_bounds__(256, 2) void gemm_mfma(const float* __restrict__ in,
                                                    const unsigned short* __restrict__ whi,
                                                    const unsigned short* __restrict__ wlo,
                                                    float* __restrict__ hs) {
    int lane = threadIdx.x & 63;
    int wid = threadIdx.x >> 6;
    int cg = wid & 1;
    int rg = wid >> 1;
    int l16 = lane & 15;
    int quad = lane >> 4;
    int koff_base = quad * 8;

    short8 bhi[4][4], blo[4][4];
#pragma unroll
    for (int t = 0; t < 4; t++) {
        int n = cg * 64 + t * 16 + l16;
#pragma unroll
        for (int ks = 0; ks < 4; ks++) {
            int koff = ks * 32 + koff_base;
            bhi[t][ks] = *(const short8*)(whi + n * DD + koff);
            blo[t][ks] = *(const short8*)(wlo + n * DD + koff);
        }
    }

#pragma unroll
    for (int chunk = 0; chunk < 4; chunk++) {
        int base = blockIdx.x * 128 + chunk * 32 + rg * 16;
        int m = base + l16;
        int mld = (m < NN) ? m : 0;
        const float* xr = in + (size_t)mld * DD;

        short8 ahi[4], alo[4];
#pragma unroll
        for (int ks = 0; ks < 4; ks++) {
            int koff = ks * 32 + koff_base;
            float4 a0 = *(const float4*)(xr + koff);
            float4 a1 = *(const float4*)(xr + koff + 4);
            float v[8] = {a0.x, a0.y, a0.z, a0.w, a1.x, a1.y, a1.z, a1.w};
#pragma unroll
            for (int j = 0; j < 8; j++) {
                float xv = RELU ? fmaxf(v[j], 0.0f) : v[j];
                unsigned short h, l;
                split_bf16(xv, h, l);
                ahi[ks][j] = (short)h;
                alo[ks][j] = (short)l;
            }
        }

        floatx4 acc[4];
#pragma unroll
        for (int t = 0; t < 4; t++) acc[t] = (floatx4)(0.0f);

#pragma unroll
        for (int ks = 0; ks < 4; ks++) {
#pragma unroll
            for (int t = 0; t < 4; t++) {
                acc[t] = __builtin_amdgcn_mfma_f32_16x16x32_bf16(ahi[ks], bhi[t][ks], acc[t], 0, 0, 0);
                acc[t] = __builtin_amdgcn_mfma_f32_16x16x32_bf16(alo[ks], bhi[t][ks], acc[t], 0, 0, 0);
                acc[t] = __builtin_amdgcn_mfma_f32_16x16x32_bf16(ahi[ks], blo[t][ks], acc[t], 0, 0, 0);
            }
        }

        // store sliced: slice = cg*4+t, within-slice col = l16
#pragma unroll
        for (int r = 0; r < 4; r++) {
            int rowm = base + quad * 4 + r;
            if (rowm < NN) {
#pragma unroll
                for (int t = 0; t < 4; t++)
                    hs[((size_t)(cg * 4 + t) * NN + rowm) * 16 + l16] = acc[t][r];
            }
        }
    }
}

// ---------------- XCD-pinned sliced aggregation ----------------
// slice = blockIdx & 7 -> (round-robin dispatch) all slice-s blocks on XCD s;
// slice working set = 3.2 MB < 4 MB L2. Wave: 16 edges in flight, 4 lanes x
// float4 per edge; shfl_xor(4,8,16,32) folds edge groups.
// out[i] = b + dis[i]*sum(ew*dis[row]*h[row]) + dis[i]^2*h[i]   (row-major out)

#define KN 4   // nodes per wave

__global__ __launch_bounds__(256) void agg_sliced(const int* __restrict__ offsets,
                                                  const uint2* __restrict__ epk,
                                                  const float* __restrict__ hs,
                                                  const float* __restrict__ dis,
                                                  const float* __restrict__ bias,
                                                  float* __restrict__ out) {
    int slice = blockIdx.x & 7;
    int nb = blockIdx.x >> 3;
    int wid = threadIdx.x >> 6;
    int lane = threadIdx.x & 63;
    int eg = lane >> 2;      // edge group 0..15
    int fl = lane & 3;       // float4 index within the 16-float slice

    const float* hslice = hs + (size_t)slice * NN * 16;
    float4 bb = ((const float4*)(bias + slice * 16))[fl];

    for (int n = 0; n < KN; n++) {
        int i = (nb * 4 + wid) * KN + n;
        if (i >= NN) break;
        int start = offsets[i], end = offsets[i + 1];

        float ax = 0.0f, ay = 0.0f, az = 0.0f, aw = 0.0f;
        for (int j = start + eg; j < end; j += 16) {
            uint2 p = epk[j];
            float nm = __uint_as_float(p.y);
            float4 v = ((const float4*)(hslice + (size_t)p.x * 16))[fl];
            ax = fmaf(nm, v.x, ax);
            ay = fmaf(nm, v.y, ay);
            az = fmaf(nm, v.z, az);
            aw = fmaf(nm, v.w, aw);
        }
#pragma unroll
        for (int m = 4; m <= 32; m <<= 1) {
            ax += __shfl_xor(ax, m);
            ay += __shfl_xor(ay, m);
            az += __shfl_xor(az, m);
            aw += __shfl_xor(aw, m);
        }
        if (eg == 0) {
            float d = dis[i];
            float d2 = d * d;
            float4 hv = ((const float4*)(hslice + (size_t)i * 16))[fl];
            float4 o;
            o.x = bb.x + d * ax + d2 * hv.x;
            o.y = bb.y + d * ay + d2 * hv.y;
            o.z = bb.z + d * az + d2 * hv.z;
            o.w = bb.w + d * aw + d2 * hv.w;
            ((float4*)(out + (size_t)i * DD + slice * 16))[fl] = o;
        }
    }
}

// ---------------- launch ----------------

extern "C" void kernel_launch(void* const* d_in, const int* in_sizes, int n_in,
                              void* d_out, int out_size, void* d_ws, size_t ws_size,
                              hipStream_t stream) {
    const float* x  = (const float*)d_in[0];
    const int*   ei = (const int*)d_in[1];
    const float* ew = (const float*)d_in[2];
    const float* W1 = (const float*)d_in[3];
    const float* b1 = (const float*)d_in[4];
    const float* W2 = (const float*)d_in[5];
    const float* b2 = (const float*)d_in[6];
    float* out = (float*)d_out;

    // workspace layout (4B words)
    float* ws      = (float*)d_ws;
    float* dis     = ws;                              // [0, 50000)
    int*   counts  = (int*)(ws + NN);                 // [50000, 250000) padded x4
    int*   offsets = counts + NN * CPAD;              // [250000, 300001)
    int*   bsum    = offsets + NN + 1;                // [300001, 300099)
    uint2* epk     = (uint2*)(ws + 300100);           // 8B-aligned; NE uint2
    float* hs      = ws + 300100 + 2 * NE;            // word 1900100, byte 7600400 (16B-aligned)
    int*   rank    = (int*)hs;                        // aliases hs: consumed before gemm writes
    unsigned short* wt1hi = (unsigned short*)(ws + 8300100);  // 8192 words each
    unsigned short* wt1lo = (unsigned short*)(ws + 8308292);
    unsigned short* wt2hi = (unsigned short*)(ws + 8316484);
    unsigned short* wt2lo = (unsigned short*)(ws + 8324676);
    // total ~8.33M words ~= 33.3 MB

    const int* rowi = ei;
    const int* coli = ei + NE;

    // ---- CSR build: 1 atomic per edge total ----
    init_kernel<<<(NN + 255) / 256, 256, 0, stream>>>(counts);
    hist_rank<<<(NE + 255) / 256, 256, 0, stream>>>(coli, counts, rank);
    block_reduce<<<NBLK, 256, 0, stream>>>(counts, bsum);
    scan_partials<<<1, 128, 0, stream>>>(bsum, offsets);
    scan_block<<<NBLK, 512, 0, stream>>>(counts, bsum, offsets);
    place_edges<<<(NE + 255) / 256, 256, 0, stream>>>(rowi, coli, ew, offsets, rank, epk);
    deg_dis<<<(NN * 4 + 255) / 256, 256, 0, stream>>>(offsets, epk, dis);
    rescale<<<(NE + 255) / 256, 256, 0, stream>>>(epk, dis);
    prep_w<<<64, 256, 0, stream>>>(W1, wt1hi, wt1lo);
    prep_w<<<64, 256, 0, stream>>>(W2, wt2hi, wt2lo);

    const int gemm_grid = (NN + 127) / 128;          // 391
    const int agg_grid  = ((NN + 4 * KN - 1) / (4 * KN)) * 8;  // 3125 * 8 = 25000

    // ---- layer 1: h1 = x @ W1 (sliced) ; out1 = A_norm h1 + b1 (row-major d_out) ----
    gemm_mfma<false><<<gemm_grid, 256, 0, stream>>>(x, wt1hi, wt1lo, hs);
    agg_sliced<<<agg_grid, 256, 0, stream>>>(offsets, epk, hs, dis, b1, out);

    // ---- layer 2: h2 = relu(out1) @ W2 (sliced) ; out = A_norm h2 + b2 ----
    gemm_mfma<true><<<gemm_grid, 256, 0, stream>>>(out, wt2hi, wt2lo, hs);
    agg_sliced<<<agg_grid, 256, 0, stream>>>(offsets, epk, hs, dis, b2, out);
}

// Round 6
// 278.969 us; speedup vs baseline: 1.4319x; 1.4319x over previous
//
#include <hip/hip_runtime.h>

#define NN 50000
#define NE 800000
#define DD 128

#define SCAN_TILE 512
#define NBLK ((NN + SCAN_TILE - 1) / SCAN_TILE)   // 98
#define CPAD 16                                    // counts: 1 bin per 64B

typedef __attribute__((ext_vector_type(8))) short short8;
typedef __attribute__((ext_vector_type(4))) float floatx4;
typedef __attribute__((ext_vector_type(4))) _Float16 half4;

// ---------------- init ----------------

__global__ void init_kernel(int* __restrict__ counts) {
    int i = blockIdx.x * blockDim.x + threadIdx.x;
    if (i < NN) counts[i * CPAD] = 0;
}

// single atomic per edge: histogram + within-node rank (padded bins)
__global__ void hist_rank(const int* __restrict__ col, int* __restrict__ counts,
                          int* __restrict__ rank) {
    int e = blockIdx.x * blockDim.x + threadIdx.x;
    if (e < NE) rank[e] = atomicAdd(&counts[col[e] * CPAD], 1);
}

// ---------------- hierarchical exclusive scan ----------------

__global__ __launch_bounds__(256) void block_reduce(const int* __restrict__ counts,
                                                    int* __restrict__ bsum) {
    __shared__ int s[256];
    int b = blockIdx.x, t = threadIdx.x;
    int i = b * SCAN_TILE + t;
    int v = 0;
    if (i < NN) v += counts[i * CPAD];
    if (i + 256 < NN && t + 256 < SCAN_TILE) v += counts[(i + 256) * CPAD];
    s[t] = v;
    __syncthreads();
    for (int o = 128; o > 0; o >>= 1) {
        if (t < o) s[t] += s[t + o];
        __syncthreads();
    }
    if (t == 0) bsum[b] = s[0];
}

__global__ __launch_bounds__(128) void scan_partials(int* __restrict__ bsum,
                                                     int* __restrict__ offsets) {
    __shared__ int s[128];
    int t = threadIdx.x;
    int v = (t < NBLK) ? bsum[t] : 0;
    s[t] = v;
    __syncthreads();
    for (int off = 1; off < 128; off <<= 1) {
        int x = (t >= off) ? s[t - off] : 0;
        __syncthreads();
        s[t] += x;
        __syncthreads();
    }
    if (t < NBLK) bsum[t] = s[t] - v;        // exclusive
    if (t == 127) offsets[NN] = s[NBLK - 1]; // == NE
}

__global__ __launch_bounds__(512) void scan_block(const int* __restrict__ counts,
                                                  const int* __restrict__ bsum,
                                                  int* __restrict__ offsets) {
    __shared__ int tmp[SCAN_TILE];
    int b = blockIdx.x, t = threadIdx.x;
    int i = b * SCAN_TILE + t;
    int v = (i < NN) ? counts[i * CPAD] : 0;
    tmp[t] = v;
    __syncthreads();
    for (int off = 1; off < SCAN_TILE; off <<= 1) {
        int x = (t >= off) ? tmp[t - off] : 0;
        __syncthreads();
        tmp[t] += x;
        __syncthreads();
    }
    if (i < NN) offsets[i] = tmp[t] - v + bsum[b];
}

// place edges into CSR slots (no atomics): epk = (row, raw ew)
__global__ void place_edges(const int* __restrict__ row, const int* __restrict__ col,
                            const float* __restrict__ ew, const int* __restrict__ offsets,
                            const int* __restrict__ rank, uint2* __restrict__ epk) {
    int e = blockIdx.x * blockDim.x + threadIdx.x;
    if (e >= NE) return;
    int c = col[e];
    uint2 p;
    p.x = (unsigned)row[e];
    p.y = __float_as_uint(ew[e]);
    epk[offsets[c] + rank[e]] = p;
}

// deg/dis from CSR: contiguous segmented sum, 4 lanes per node
__global__ void deg_dis(const int* __restrict__ offsets, const uint2* __restrict__ epk,
                        float* __restrict__ dis) {
    int t = blockIdx.x * blockDim.x + threadIdx.x;
    int i = t >> 2, l = t & 3;
    if (i >= NN) return;
    float s = 0.0f;
    int start = offsets[i], end = offsets[i + 1];
    for (int j = start + l; j < end; j += 4) s += __uint_as_float(epk[j].y);
    s += __shfl_xor(s, 1);
    s += __shfl_xor(s, 2);
    if (l == 0) dis[i] = rsqrtf(fmaxf(1.0f + s, 1e-12f));  // +1 self-loop
}

// epk.y: ew -> ew * dis[row]  (once for both layers)
__global__ void rescale(uint2* __restrict__ epk, const float* __restrict__ dis) {
    int e = blockIdx.x * blockDim.x + threadIdx.x;
    if (e < NE) {
        uint2 p = epk[e];
        epk[e].y = __float_as_uint(__uint_as_float(p.y) * dis[p.x]);
    }
}

// ---------------- bf16x3 split helpers ----------------

__device__ __forceinline__ void split_bf16(float x, unsigned short& hi, unsigned short& lo) {
    unsigned u = __float_as_uint(x);
    unsigned h = (u + 0x7FFFu + ((u >> 16) & 1u)) >> 16;   // RN-even to bf16
    hi = (unsigned short)h;
    float fh = __uint_as_float(h << 16);
    float r = x - fh;
    unsigned u2 = __float_as_uint(r);
    lo = (unsigned short)((u2 + 0x7FFFu + ((u2 >> 16) & 1u)) >> 16);
}

__global__ void prep_w(const float* __restrict__ W, unsigned short* __restrict__ whi,
                       unsigned short* __restrict__ wlo) {
    int t = blockIdx.x * blockDim.x + threadIdx.x;   // 16384
    int k = t >> 7, n = t & 127;
    unsigned short h, l;
    split_bf16(W[t], h, l);
    whi[n * DD + k] = h;
    wlo[n * DD + k] = l;
}

// ---------------- MFMA GEMM: h[m,128] (fp16) = (relu?)in[m,128] @ W ----------------

template <bool RELU>
__global__ __launch_bounds__(256, 2) void gemm_mfma(const float* __restrict__ in,
                                                    const unsigned short* __restrict__ whi,
                                                    const unsigned short* __restrict__ wlo,
                                                    _Float16* __restrict__ out) {
    int lane = threadIdx.x & 63;
    int wid = threadIdx.x >> 6;
    int cg = wid & 1;
    int rg = wid >> 1;
    int l16 = lane & 15;
    int quad = lane >> 4;
    int koff_base = quad * 8;

    short8 bhi[4][4], blo[4][4];
#pragma unroll
    for (int t = 0; t < 4; t++) {
        int n = cg * 64 + t * 16 + l16;
#pragma unroll
        for (int ks = 0; ks < 4; ks++) {
            int koff = ks * 32 + koff_base;
            bhi[t][ks] = *(const short8*)(whi + n * DD + koff);
            blo[t][ks] = *(const short8*)(wlo + n * DD + koff);
        }
    }

#pragma unroll
    for (int chunk = 0; chunk < 4; chunk++) {
        int base = blockIdx.x * 128 + chunk * 32 + rg * 16;
        int m = base + l16;
        int mld = (m < NN) ? m : 0;
        const float* xr = in + (size_t)mld * DD;

        short8 ahi[4], alo[4];
#pragma unroll
        for (int ks = 0; ks < 4; ks++) {
            int koff = ks * 32 + koff_base;
            float4 a0 = *(const float4*)(xr + koff);
            float4 a1 = *(const float4*)(xr + koff + 4);
            float v[8] = {a0.x, a0.y, a0.z, a0.w, a1.x, a1.y, a1.z, a1.w};
#pragma unroll
            for (int j = 0; j < 8; j++) {
                float xv = RELU ? fmaxf(v[j], 0.0f) : v[j];
                unsigned short h, l;
                split_bf16(xv, h, l);
                ahi[ks][j] = (short)h;
                alo[ks][j] = (short)l;
            }
        }

        floatx4 acc[4];
#pragma unroll
        for (int t = 0; t < 4; t++) acc[t] = (floatx4)(0.0f);

#pragma unroll
        for (int ks = 0; ks < 4; ks++) {
#pragma unroll
            for (int t = 0; t < 4; t++) {
                acc[t] = __builtin_amdgcn_mfma_f32_16x16x32_bf16(ahi[ks], bhi[t][ks], acc[t], 0, 0, 0);
                acc[t] = __builtin_amdgcn_mfma_f32_16x16x32_bf16(alo[ks], bhi[t][ks], acc[t], 0, 0, 0);
                acc[t] = __builtin_amdgcn_mfma_f32_16x16x32_bf16(ahi[ks], blo[t][ks], acc[t], 0, 0, 0);
            }
        }

#pragma unroll
        for (int r = 0; r < 4; r++) {
            int rowm = base + quad * 4 + r;
            if (rowm < NN) {
                _Float16* o = out + (size_t)rowm * DD + cg * 64 + l16;
#pragma unroll
                for (int t = 0; t < 4; t++) o[t * 16] = (_Float16)acc[t][r];
            }
        }
    }
}

// ---------------- CSR gather aggregation (fp16 h, f32 accumulate) ----------------
// One wave per node; half-waves take edges j / j+1, 4x unrolled -> 8 gathers
// in flight. Lane s of each half owns 4 features (half4 = 8B); row = 256 B.
// out[i] = b + dis[i]*sum(ew*dis[row]*h[row]) + dis[i]^2*h[i]

__global__ __launch_bounds__(256) void agg_half(const int* __restrict__ offsets,
                                                const uint2* __restrict__ epk,
                                                const _Float16* __restrict__ h,
                                                const float* __restrict__ dis,
                                                const float* __restrict__ bias,
                                                float* __restrict__ out) {
    int i = (blockIdx.x * blockDim.x + threadIdx.x) >> 6;   // node
    int lane = threadIdx.x & 63;
    int s = lane & 31;
    int half = lane >> 5;
    if (i >= NN) return;

    float ax = 0.0f, ay = 0.0f, az = 0.0f, aw = 0.0f;

    int start = offsets[i], end = offsets[i + 1];
    int j = start + half;
    for (; j + 6 < end; j += 8) {
        uint2 p0 = epk[j], p1 = epk[j + 2], p2 = epk[j + 4], p3 = epk[j + 6];
        half4 v0 = *(const half4*)(h + (size_t)p0.x * DD + s * 4);
        half4 v1 = *(const half4*)(h + (size_t)p1.x * DD + s * 4);
        half4 v2 = *(const half4*)(h + (size_t)p2.x * DD + s * 4);
        half4 v3 = *(const half4*)(h + (size_t)p3.x * DD + s * 4);
        float n0 = __uint_as_float(p0.y), n1 = __uint_as_float(p1.y);
        float n2 = __uint_as_float(p2.y), n3 = __uint_as_float(p3.y);
        ax = fmaf(n0, (float)v0.x, ax); ay = fmaf(n0, (float)v0.y, ay);
        az = fmaf(n0, (float)v0.z, az); aw = fmaf(n0, (float)v0.w, aw);
        ax = fmaf(n1, (float)v1.x, ax); ay = fmaf(n1, (float)v1.y, ay);
        az = fmaf(n1, (float)v1.z, az); aw = fmaf(n1, (float)v1.w, aw);
        ax = fmaf(n2, (float)v2.x, ax); ay = fmaf(n2, (float)v2.y, ay);
        az = fmaf(n2, (float)v2.z, az); aw = fmaf(n2, (float)v2.w, aw);
        ax = fmaf(n3, (float)v3.x, ax); ay = fmaf(n3, (float)v3.y, ay);
        az = fmaf(n3, (float)v3.z, az); aw = fmaf(n3, (float)v3.w, aw);
    }
    for (; j < end; j += 2) {
        uint2 p = epk[j];
        float nm = __uint_as_float(p.y);
        half4 v = *(const half4*)(h + (size_t)p.x * DD + s * 4);
        ax = fmaf(nm, (float)v.x, ax); ay = fmaf(nm, (float)v.y, ay);
        az = fmaf(nm, (float)v.z, az); aw = fmaf(nm, (float)v.w, aw);
    }

    ax += __shfl_xor(ax, 32);
    ay += __shfl_xor(ay, 32);
    az += __shfl_xor(az, 32);
    aw += __shfl_xor(aw, 32);

    if (half == 0) {
        float d = dis[i];
        float d2 = d * d;
        half4 hv = *(const half4*)(h + (size_t)i * DD + s * 4);
        float4 bb = ((const float4*)bias)[s >> 2];
        float bx = (s & 3) == 0 ? bb.x : ((s & 3) == 1 ? bb.y : ((s & 3) == 2 ? bb.z : bb.w));
        // simpler: reload bias scalar-wise (bias is tiny, L1-resident)
        const float* bp = bias + s * 4;
        float4 o;
        o.x = bp[0] + d * ax + d2 * (float)hv.x;
        o.y = bp[1] + d * ay + d2 * (float)hv.y;
        o.z = bp[2] + d * az + d2 * (float)hv.z;
        o.w = bp[3] + d * aw + d2 * (float)hv.w;
        (void)bx;
        ((float4*)(out + (size_t)i * DD))[s] = o;
    }
}

// ---------------- launch ----------------

extern "C" void kernel_launch(void* const* d_in, const int* in_sizes, int n_in,
                              void* d_out, int out_size, void* d_ws, size_t ws_size,
                              hipStream_t stream) {
    const float* x  = (const float*)d_in[0];
    const int*   ei = (const int*)d_in[1];
    const float* ew = (const float*)d_in[2];
    const float* W1 = (const float*)d_in[3];
    const float* b1 = (const float*)d_in[4];
    const float* W2 = (const float*)d_in[5];
    const float* b2 = (const float*)d_in[6];
    float* out = (float*)d_out;

    // workspace layout (4B words)
    float* ws      = (float*)d_ws;
    float* dis     = ws;                              // [0, 50000)
    int*   counts  = (int*)(ws + NN);                 // [50000, 850000) padded x16
    int*   offsets = counts + NN * CPAD;              // [850000, 900001)
    int*   bsum    = offsets + NN + 1;                // [900001, 900099)
    uint2* epk     = (uint2*)(ws + 900100);           // 8B-aligned; NE uint2
    _Float16* hbuf = (_Float16*)(ws + 900100 + 2 * NE);  // word 2500100, 16B-aligned; NN*DD fp16
    int*   rank    = (int*)hbuf;                      // aliases hbuf: consumed before gemm writes
    unsigned short* wt1hi = (unsigned short*)(ws + 5700100);  // 8192 words each
    unsigned short* wt1lo = (unsigned short*)(ws + 5708292);
    unsigned short* wt2hi = (unsigned short*)(ws + 5716484);
    unsigned short* wt2lo = (unsigned short*)(ws + 5724676);
    // total ~5.73M words ~= 22.9 MB

    const int* rowi = ei;
    const int* coli = ei + NE;

    // ---- CSR build: 1 atomic per edge total ----
    init_kernel<<<(NN + 255) / 256, 256, 0, stream>>>(counts);
    hist_rank<<<(NE + 255) / 256, 256, 0, stream>>>(coli, counts, rank);
    block_reduce<<<NBLK, 256, 0, stream>>>(counts, bsum);
    scan_partials<<<1, 128, 0, stream>>>(bsum, offsets);
    scan_block<<<NBLK, 512, 0, stream>>>(counts, bsum, offsets);
    place_edges<<<(NE + 255) / 256, 256, 0, stream>>>(rowi, coli, ew, offsets, rank, epk);
    deg_dis<<<(NN * 4 + 255) / 256, 256, 0, stream>>>(offsets, epk, dis);
    rescale<<<(NE + 255) / 256, 256, 0, stream>>>(epk, dis);
    prep_w<<<64, 256, 0, stream>>>(W1, wt1hi, wt1lo);
    prep_w<<<64, 256, 0, stream>>>(W2, wt2hi, wt2lo);

    const int gemm_grid = (NN + 127) / 128;  // 391

    // ---- layer 1: h1 = x @ W1 (fp16) ; out1 = A_norm h1 + b1 (f32, d_out) ----
    gemm_mfma<false><<<gemm_grid, 256, 0, stream>>>(x, wt1hi, wt1lo, hbuf);
    agg_half<<<(NN * 64) / 256 + 1, 256, 0, stream>>>(offsets, epk, hbuf, dis, b1, out);

    // ---- layer 2: h2 = relu(out1) @ W2 (fp16) ; out = A_norm h2 + b2 ----
    gemm_mfma<true><<<gemm_grid, 256, 0, stream>>>(out, wt2hi, wt2lo, hbuf);
    agg_half<<<(NN * 64) / 256 + 1, 256, 0, stream>>>(offsets, epk, hbuf, dis, b2, out);
}